// Round 1
// baseline (73.505 us; speedup 1.0000x reference)
//
#include <hip/hip_runtime.h>

#define Bc 8
#define Nc 360
#define Dc 128
#define BN (Bc * Nc)        // 2880 rows
#define TILE 64
#define NT 6                // ceil(360/64)
#define LDST 132            // LDS row stride (floats): 132 mod 32 = 4 -> <=2-way banks

// Kernel 1: S[row,d] = sum_f W1[d,f]      * emb[row,f]            (sender proj, j-indexed)
//           R[row,d] = sum_f W1[d,128+f]  * emb[row,f] + b1[d]    (receiver proj, i-indexed)
__global__ __launch_bounds__(256) void proj_kernel(
    const float* __restrict__ emb, const float* __restrict__ W1,
    const float* __restrict__ b1, float* __restrict__ S, float* __restrict__ R)
{
    const int lane = threadIdx.x & 63;
    const int w    = threadIdx.x >> 6;                       // wave 0..3
    const int row  = __builtin_amdgcn_readfirstlane(blockIdx.x * 4 + w); // wave-uniform
    const int c    = blockIdx.y * 64 + lane;                 // 0..255 (uniform half per wave)

    const float* e = emb + row * Dc;                         // uniform -> scalar loads
    const float* wchunk;
    float acc;
    if (c < Dc) { wchunk = W1 + c * (2 * Dc);            acc = 0.0f;      }
    else        { wchunk = W1 + (c - Dc) * (2 * Dc) + Dc; acc = b1[c - Dc]; }

    #pragma unroll 8
    for (int f4 = 0; f4 < Dc / 4; ++f4) {
        float4 w4 = reinterpret_cast<const float4*>(wchunk)[f4];
        float4 e4 = reinterpret_cast<const float4*>(e)[f4];
        acc = fmaf(w4.x, e4.x, acc);
        acc = fmaf(w4.y, e4.y, acc);
        acc = fmaf(w4.z, e4.z, acc);
        acc = fmaf(w4.w, e4.w, acc);
    }
    if (c < Dc) S[row * Dc + c] = acc;
    else        R[row * Dc + (c - Dc)] = acc;
}

// Kernel 2: out[b,i,j] = relu( b2 + sum_d w2[d] * relu(S[b,j,d] + R[b,i,d]) )
__global__ __launch_bounds__(256) void edge_kernel(
    const float* __restrict__ S, const float* __restrict__ R,
    const float* __restrict__ W2, const float* __restrict__ b2,
    float* __restrict__ out)
{
    __shared__ float S_s[TILE * LDST];   // sender rows (j)
    __shared__ float R_s[TILE * LDST];   // receiver rows (i)
    __shared__ float w2_s[Dc];

    const int t  = threadIdx.x;
    const int b  = blockIdx.z;
    const int i0 = blockIdx.y * TILE;
    const int j0 = blockIdx.x * TILE;

    // ---- stage panels (coalesced float4 loads, clamped rows for the tail tile)
    {
        const int r0 = t >> 5;            // 0..7
        const int c4 = (t & 31) * 4;      // float4 column
        #pragma unroll
        for (int p = 0; p < 8; ++p) {
            const int rr = p * 8 + r0;    // 0..63
            int jr = j0 + rr; if (jr > Nc - 1) jr = Nc - 1;
            int ir = i0 + rr; if (ir > Nc - 1) ir = Nc - 1;
            *reinterpret_cast<float4*>(&S_s[rr * LDST + c4]) =
                *reinterpret_cast<const float4*>(&S[(b * Nc + jr) * Dc + c4]);
            *reinterpret_cast<float4*>(&R_s[rr * LDST + c4]) =
                *reinterpret_cast<const float4*>(&R[(b * Nc + ir) * Dc + c4]);
        }
        if (t < Dc) w2_s[t] = W2[t];
    }
    __syncthreads();

    const int ti = t >> 4;    // 0..15 -> i = i0 + ti + 16*ii
    const int tj = t & 15;    // 0..15 -> j = j0 + tj + 16*jj

    float acc[4][4];
    #pragma unroll
    for (int ii = 0; ii < 4; ++ii)
        #pragma unroll
        for (int jj = 0; jj < 4; ++jj) acc[ii][jj] = 0.0f;

    #pragma unroll 4
    for (int d4 = 0; d4 < Dc; d4 += 4) {
        const float4 w4 = *reinterpret_cast<const float4*>(&w2_s[d4]);
        float4 rv[4], sv[4];
        #pragma unroll
        for (int ii = 0; ii < 4; ++ii)
            rv[ii] = *reinterpret_cast<const float4*>(&R_s[(ti + 16 * ii) * LDST + d4]);
        #pragma unroll
        for (int jj = 0; jj < 4; ++jj)
            sv[jj] = *reinterpret_cast<const float4*>(&S_s[(tj + 16 * jj) * LDST + d4]);
        #pragma unroll
        for (int ii = 0; ii < 4; ++ii)
            #pragma unroll
            for (int jj = 0; jj < 4; ++jj) {
                acc[ii][jj] = fmaf(w4.x, fmaxf(rv[ii].x + sv[jj].x, 0.0f), acc[ii][jj]);
                acc[ii][jj] = fmaf(w4.y, fmaxf(rv[ii].y + sv[jj].y, 0.0f), acc[ii][jj]);
                acc[ii][jj] = fmaf(w4.z, fmaxf(rv[ii].z + sv[jj].z, 0.0f), acc[ii][jj]);
                acc[ii][jj] = fmaf(w4.w, fmaxf(rv[ii].w + sv[jj].w, 0.0f), acc[ii][jj]);
            }
    }

    const float bias2 = b2[0];
    #pragma unroll
    for (int ii = 0; ii < 4; ++ii) {
        const int ig = i0 + ti + 16 * ii;
        if (ig >= Nc) continue;
        #pragma unroll
        for (int jj = 0; jj < 4; ++jj) {
            const int jg = j0 + tj + 16 * jj;
            if (jg >= Nc) continue;
            out[(b * Nc + ig) * Nc + jg] = fmaxf(acc[ii][jj] + bias2, 0.0f);
        }
    }
}

extern "C" void kernel_launch(void* const* d_in, const int* in_sizes, int n_in,
                              void* d_out, int out_size, void* d_ws, size_t ws_size,
                              hipStream_t stream) {
    const float* emb = (const float*)d_in[0];   // [B,N,D]
    const float* W1  = (const float*)d_in[1];   // [D, 2D]
    const float* b1  = (const float*)d_in[2];   // [D]
    const float* W2  = (const float*)d_in[3];   // [1, D]
    const float* b2  = (const float*)d_in[4];   // [1]
    float* out = (float*)d_out;                 // [B,N,N,1]

    float* S = (float*)d_ws;                    // [B*N, D] sender proj
    float* R = S + BN * Dc;                     // [B*N, D] receiver proj (+b1)

    proj_kernel<<<dim3(BN / 4, 4), 256, 0, stream>>>(emb, W1, b1, S, R);
    edge_kernel<<<dim3(NT, NT, Bc), 256, 0, stream>>>(S, R, W2, b2, out);
}